// Round 1
// baseline (559.458 us; speedup 1.0000x reference)
//
#include <hip/hip_runtime.h>

#define NS 65536      // B*H*W samples
#define D 64          // embed dim
#define K 1024        // codebook size
#define NEL 4194304   // NS*D

// ---------------------------------------------------------------------------
// Prep: transpose codebook [D,K] -> [K,D] (contiguous 256B rows), compute
// ||m_k||^2, zero the loss accumulator.
// ---------------------------------------------------------------------------
__global__ __launch_bounds__(256) void vq_prep(
    const float* __restrict__ cm,   // [D,K]
    float* __restrict__ ct,         // [K,D]
    float* __restrict__ cnorm,      // [K]
    double* __restrict__ acc)
{
    const int k = blockIdx.x * 256 + threadIdx.x;   // 4 blocks x 256 = 1024
    if (k == 0) *acc = 0.0;
    float vals[D];
    float n = 0.f;
#pragma unroll
    for (int d = 0; d < D; ++d) {
        float v = cm[d * K + k];    // coalesced across k
        vals[d] = v;
        n = fmaf(v, v, n);
    }
    cnorm[k] = n;
    float4* dst = (float4*)(ct + (size_t)k * D);
#pragma unroll
    for (int j = 0; j < D / 4; ++j)
        dst[j] = make_float4(vals[4*j], vals[4*j+1], vals[4*j+2], vals[4*j+3]);
}

// ---------------------------------------------------------------------------
// Main: 1024 blocks x 256 threads. Block = 64 samples x 4 K-partitions.
// Each thread: sample x[64] in VGPRs, scans 256 codes (wave-uniform codebook
// address -> scalar loads), tracks strict-first argmin.
// ---------------------------------------------------------------------------
__global__ __launch_bounds__(256) void vq_main(
    const float* __restrict__ xin,    // [NS,D]
    const float* __restrict__ ct,     // [K,D]
    const float* __restrict__ cnorm,  // [K]
    float* __restrict__ outq,         // [NS,D]
    float* __restrict__ outidx,       // [NS] (indices as float)
    double* __restrict__ acc)
{
    const int lane = threadIdx.x & 63;   // sample within block
    const int part = threadIdx.x >> 6;   // K-partition 0..3
    const int s = blockIdx.x * 64 + lane;

    // load sample into registers
    const float* xp = xin + (size_t)s * D;
    float x[D];
#pragma unroll
    for (int d = 0; d < D; d += 4) {
        float4 v = *(const float4*)(xp + d);
        x[d] = v.x; x[d+1] = v.y; x[d+2] = v.z; x[d+3] = v.w;
    }

    float best = 3.4e38f;
    int bi = 0;
    const int k0 = part * (K / 4);
    for (int k = k0; k < k0 + K / 4; ++k) {
        const float* __restrict__ m = ct + ((size_t)k << 6);  // wave-uniform
        float a0 = 0.f, a1 = 0.f, a2 = 0.f, a3 = 0.f;
#pragma unroll
        for (int d = 0; d < D; d += 4) {
            a0 = fmaf(x[d],     m[d],     a0);
            a1 = fmaf(x[d + 1], m[d + 1], a1);
            a2 = fmaf(x[d + 2], m[d + 2], a2);
            a3 = fmaf(x[d + 3], m[d + 3], a3);
        }
        float dot = (a0 + a1) + (a2 + a3);
        float dist = fmaf(-2.f, dot, cnorm[k]);   // ||m||^2 - 2 x.m
        if (dist < best) { best = dist; bi = k; } // strict < keeps first min
    }

    // combine the 4 partitions per sample (ascending part = ascending k,
    // strict < preserves numpy first-occurrence argmin tie-break)
    __shared__ float sb[4][64];
    __shared__ int   si[4][64];
    __shared__ int   widx[64];
    sb[part][lane] = best;
    si[part][lane] = bi;
    __syncthreads();
    if (part == 0) {
        float b = sb[0][lane];
        int   w = si[0][lane];
#pragma unroll
        for (int p = 1; p < 4; ++p) {
            float bp = sb[p][lane];
            if (bp < b) { b = bp; w = si[p][lane]; }
        }
        widx[lane] = w;
    }
    __syncthreads();

    // gather + STE output + loss partial: thread t handles 16 dims of one sample
    const int sl = threadIdx.x >> 2;          // local sample 0..63
    const int d0 = (threadIdx.x & 3) * 16;    // dim offset
    const int gs = blockIdx.x * 64 + sl;
    const int w  = widx[sl];
    const float* mq = ct + ((size_t)w << 6) + d0;
    const float* xr = xin + (size_t)gs * D + d0;
    float*       oq = outq + (size_t)gs * D + d0;
    float psum = 0.f;
#pragma unroll
    for (int j = 0; j < 16; j += 4) {
        float4 q  = *(const float4*)(mq + j);
        float4 xv = *(const float4*)(xr + j);
        float4 o;
        float dx = q.x - xv.x, dy = q.y - xv.y, dz = q.z - xv.z, dw = q.w - xv.w;
        o.x = xv.x + dx; o.y = xv.y + dy; o.z = xv.z + dz; o.w = xv.w + dw;
        *(float4*)(oq + j) = o;
        psum = fmaf(dx, dx, psum);
        psum = fmaf(dy, dy, psum);
        psum = fmaf(dz, dz, psum);
        psum = fmaf(dw, dw, psum);
    }

    if (threadIdx.x < 64)
        outidx[blockIdx.x * 64 + threadIdx.x] = (float)widx[threadIdx.x];

    // block reduce loss partials, one double atomic per block
    __shared__ float red[256];
    red[threadIdx.x] = psum;
    __syncthreads();
    for (int st = 128; st > 0; st >>= 1) {
        if (threadIdx.x < st) red[threadIdx.x] += red[threadIdx.x + st];
        __syncthreads();
    }
    if (threadIdx.x == 0) atomicAdd(acc, (double)red[0]);
}

// ---------------------------------------------------------------------------
// Finalize: loss = m + 0.25*m where m = mean((q-x)^2), mimicking reference
// q_loss + 0.25*e_loss rounding.
// ---------------------------------------------------------------------------
__global__ void vq_finalize(const double* __restrict__ acc,
                            float* __restrict__ loss_out)
{
    float m = (float)(*acc / (double)NEL);
    *loss_out = m + 0.25f * m;
}

extern "C" void kernel_launch(void* const* d_in, const int* in_sizes, int n_in,
                              void* d_out, int out_size, void* d_ws, size_t ws_size,
                              hipStream_t stream) {
    const float* xin = (const float*)d_in[0];   // [16,64,64,64] fp32
    const float* cm  = (const float*)d_in[1];   // [64,1024] fp32

    float* out     = (float*)d_out;
    float* outq    = out;                 // 4194304 floats
    float* outidx  = out + NEL;           // 65536 floats (indices)
    float* outloss = out + NEL + NS;      // 1 float

    float*  ct    = (float*)d_ws;         // 65536 floats = 256 KB
    float*  cnorm = ct + (size_t)K * D;   // 1024 floats
    double* acc   = (double*)(cnorm + K); // byte offset 266240, 8B-aligned

    vq_prep<<<4, 256, 0, stream>>>(cm, ct, cnorm, acc);
    vq_main<<<1024, 256, 0, stream>>>(xin, ct, cnorm, outq, outidx, acc);
    vq_finalize<<<1, 1, 0, stream>>>(acc, outloss);
}

// Round 2
// 250.838 us; speedup vs baseline: 2.2304x; 2.2304x over previous
//
#include <hip/hip_runtime.h>

#define NS 65536      // B*H*W samples
#define D 64          // embed dim
#define K 1024        // codebook size
#define NEL 4194304   // NS*D

// ---------------------------------------------------------------------------
// Prep: transpose codebook [D,K] -> [K,D] (contiguous 256B rows), compute
// ||m_k||^2, zero the loss accumulator.
// ---------------------------------------------------------------------------
__global__ __launch_bounds__(256) void vq_prep(
    const float* __restrict__ cm,   // [D,K]
    float* __restrict__ ct,         // [K,D]
    float* __restrict__ cnorm,      // [K]
    double* __restrict__ acc)
{
    const int k = blockIdx.x * 256 + threadIdx.x;   // 4 blocks x 256 = 1024
    if (k == 0) *acc = 0.0;
    float vals[D];
    float n = 0.f;
#pragma unroll
    for (int d = 0; d < D; ++d) {
        float v = cm[d * K + k];    // coalesced across k
        vals[d] = v;
        n = fmaf(v, v, n);
    }
    cnorm[k] = n;
    float4* dst = (float4*)(ct + (size_t)k * D);
#pragma unroll
    for (int j = 0; j < D / 4; ++j)
        dst[j] = make_float4(vals[4*j], vals[4*j+1], vals[4*j+2], vals[4*j+3]);
}

// ---------------------------------------------------------------------------
// Main: 1024 blocks x 256 threads. Block = 64 samples x 4 K-partitions.
// Each thread: sample x[64] in VGPRs. Codebook pointer is made provably
// wave-uniform via readfirstlane so the compiler promotes codebook reads to
// SGPR s_load (scalar pipe) -> hot loop is pure v_fmac_f32 v,s,v with zero
// vector-memory instructions.
// ---------------------------------------------------------------------------
__global__ __launch_bounds__(256) void vq_main(
    const float* __restrict__ xin,    // [NS,D]
    const float* __restrict__ ct,     // [K,D]
    const float* __restrict__ cnorm,  // [K]
    float* __restrict__ outq,         // [NS,D]
    float* __restrict__ outidx,       // [NS] (indices as float)
    double* __restrict__ acc)
{
    const int lane = threadIdx.x & 63;   // sample within block
    const int part = threadIdx.x >> 6;   // K-partition 0..3 (wave-uniform)
    const int s = blockIdx.x * 64 + lane;

    // load sample into registers
    const float* xp = xin + (size_t)s * D;
    float x[D];
#pragma unroll
    for (int d = 0; d < D; d += 4) {
        float4 v = *(const float4*)(xp + d);
        x[d] = v.x; x[d+1] = v.y; x[d+2] = v.z; x[d+3] = v.w;
    }

    // provably-uniform codebook partition pointers -> SMEM promotion
    const int upart = __builtin_amdgcn_readfirstlane(part);
    const float* __restrict__ mb = ct + ((size_t)upart << 14);     // *256*64
    const float* __restrict__ cn = cnorm + (upart << 8);           // *256

    float best = 3.4e38f;
    int bi = 0;
#pragma unroll 2
    for (int kk = 0; kk < K / 4; ++kk) {
        const float* __restrict__ m = mb + (kk << 6);  // uniform address
        float a0 = 0.f, a1 = 0.f, a2 = 0.f, a3 = 0.f;
#pragma unroll
        for (int d = 0; d < D; d += 4) {
            a0 = fmaf(x[d],     m[d],     a0);
            a1 = fmaf(x[d + 1], m[d + 1], a1);
            a2 = fmaf(x[d + 2], m[d + 2], a2);
            a3 = fmaf(x[d + 3], m[d + 3], a3);
        }
        float dot = (a0 + a1) + (a2 + a3);
        float dist = fmaf(-2.f, dot, cn[kk]);     // ||m||^2 - 2 x.m
        if (dist < best) { best = dist; bi = kk; } // strict < keeps first min
    }
    bi += (upart << 8);   // global code index

    // combine the 4 partitions per sample (ascending part = ascending k,
    // strict < preserves numpy first-occurrence argmin tie-break)
    __shared__ float sb[4][64];
    __shared__ int   si[4][64];
    __shared__ int   widx[64];
    sb[part][lane] = best;
    si[part][lane] = bi;
    __syncthreads();
    if (part == 0) {
        float b = sb[0][lane];
        int   w = si[0][lane];
#pragma unroll
        for (int p = 1; p < 4; ++p) {
            float bp = sb[p][lane];
            if (bp < b) { b = bp; w = si[p][lane]; }
        }
        widx[lane] = w;
    }
    __syncthreads();

    // gather + STE output + loss partial: thread t handles 16 dims of one sample
    const int sl = threadIdx.x >> 2;          // local sample 0..63
    const int d0 = (threadIdx.x & 3) * 16;    // dim offset
    const int gs = blockIdx.x * 64 + sl;
    const int w  = widx[sl];
    const float* mq = ct + ((size_t)w << 6) + d0;
    const float* xr = xin + (size_t)gs * D + d0;
    float*       oq = outq + (size_t)gs * D + d0;
    float psum = 0.f;
#pragma unroll
    for (int j = 0; j < 16; j += 4) {
        float4 q  = *(const float4*)(mq + j);
        float4 xv = *(const float4*)(xr + j);
        float4 o;
        float dx = q.x - xv.x, dy = q.y - xv.y, dz = q.z - xv.z, dw = q.w - xv.w;
        o.x = xv.x + dx; o.y = xv.y + dy; o.z = xv.z + dz; o.w = xv.w + dw;
        *(float4*)(oq + j) = o;
        psum = fmaf(dx, dx, psum);
        psum = fmaf(dy, dy, psum);
        psum = fmaf(dz, dz, psum);
        psum = fmaf(dw, dw, psum);
    }

    if (threadIdx.x < 64)
        outidx[blockIdx.x * 64 + threadIdx.x] = (float)widx[threadIdx.x];

    // block reduce loss partials, one double atomic per block
    __shared__ float red[256];
    red[threadIdx.x] = psum;
    __syncthreads();
    for (int st = 128; st > 0; st >>= 1) {
        if (threadIdx.x < st) red[threadIdx.x] += red[threadIdx.x + st];
        __syncthreads();
    }
    if (threadIdx.x == 0) atomicAdd(acc, (double)red[0]);
}

// ---------------------------------------------------------------------------
// Finalize: loss = m + 0.25*m where m = mean((q-x)^2), mimicking reference
// q_loss + 0.25*e_loss rounding.
// ---------------------------------------------------------------------------
__global__ void vq_finalize(const double* __restrict__ acc,
                            float* __restrict__ loss_out)
{
    float m = (float)(*acc / (double)NEL);
    *loss_out = m + 0.25f * m;
}

extern "C" void kernel_launch(void* const* d_in, const int* in_sizes, int n_in,
                              void* d_out, int out_size, void* d_ws, size_t ws_size,
                              hipStream_t stream) {
    const float* xin = (const float*)d_in[0];   // [16,64,64,64] fp32
    const float* cm  = (const float*)d_in[1];   // [64,1024] fp32

    float* out     = (float*)d_out;
    float* outq    = out;                 // 4194304 floats
    float* outidx  = out + NEL;           // 65536 floats (indices)
    float* outloss = out + NEL + NS;      // 1 float

    float*  ct    = (float*)d_ws;         // 65536 floats = 256 KB
    float*  cnorm = ct + (size_t)K * D;   // 1024 floats
    double* acc   = (double*)(cnorm + K); // byte offset 266240, 8B-aligned

    vq_prep<<<4, 256, 0, stream>>>(cm, ct, cnorm, acc);
    vq_main<<<1024, 256, 0, stream>>>(xin, ct, cnorm, outq, outidx, acc);
    vq_finalize<<<1, 1, 0, stream>>>(acc, outloss);
}

// Round 3
// 210.397 us; speedup vs baseline: 2.6591x; 1.1922x over previous
//
#include <hip/hip_runtime.h>

#define NS 65536      // B*H*W samples
#define D 64          // embed dim
#define K 1024        // codebook size
#define NEL 4194304   // NS*D

// ---------------------------------------------------------------------------
// Prep: transpose codebook [D,K] -> [K,D] (contiguous 256B rows), compute
// ||m_k||^2, zero the loss accumulator.
// ---------------------------------------------------------------------------
__global__ __launch_bounds__(256) void vq_prep(
    const float* __restrict__ cm,   // [D,K]
    float* __restrict__ ct,         // [K,D]
    float* __restrict__ cnorm,      // [K]
    double* __restrict__ acc)
{
    const int k = blockIdx.x * 256 + threadIdx.x;   // 4 blocks x 256 = 1024
    if (k == 0) *acc = 0.0;
    float vals[D];
    float n = 0.f;
#pragma unroll
    for (int d = 0; d < D; ++d) {
        float v = cm[d * K + k];    // coalesced across k
        vals[d] = v;
        n = fmaf(v, v, n);
    }
    cnorm[k] = n;
    float4* dst = (float4*)(ct + (size_t)k * D);
#pragma unroll
    for (int j = 0; j < D / 4; ++j)
        dst[j] = make_float4(vals[4*j], vals[4*j+1], vals[4*j+2], vals[4*j+3]);
}

// ---------------------------------------------------------------------------
// Main: register-tiled VALU GEMM. 1024 blocks x 256 threads.
// Block = 64 samples x 1024 codes (4 tiles of 256). Thread = 8 samples x 8
// codes (64 fp32 accumulators). x staged transposed [d][s] in LDS (2-way
// bank reads = free); m rows streamed per-lane-distinct from L2-resident ct.
// ---------------------------------------------------------------------------
__global__ __launch_bounds__(256, 3) void vq_main(
    const float* __restrict__ xin,    // [NS,D]
    const float* __restrict__ ct,     // [K,D]
    const float* __restrict__ cnorm,  // [K]
    float* __restrict__ outq,         // [NS,D]
    float* __restrict__ outidx,       // [NS] (indices as float)
    double* __restrict__ acc_g)
{
    __shared__ float x_lds[D * 64];   // [d][s], 16 KB
    __shared__ float sbv[32][64];
    __shared__ int   siv[32][64];
    __shared__ int   widx[64];
    __shared__ float red[256];

    const int tx = threadIdx.x;
    const int sg = tx & 7;      // sample octet 0..7  (8 samples each)
    const int kg = tx >> 3;     // code lane 0..31
    const int S0 = blockIdx.x * 64;

    // ---- stage x transposed into LDS: [d][s] ----
    {
        const int s  = tx >> 2;          // 0..63
        const int d0 = (tx & 3) * 16;    // 0/16/32/48
        const float* gp = xin + (size_t)(S0 + s) * D + d0;
        float4 v[4];
#pragma unroll
        for (int q = 0; q < 4; ++q) v[q] = ((const float4*)gp)[q];
#pragma unroll
        for (int q = 0; q < 4; ++q) {
            x_lds[(d0 + 4*q + 0) * 64 + s] = v[q].x;
            x_lds[(d0 + 4*q + 1) * 64 + s] = v[q].y;
            x_lds[(d0 + 4*q + 2) * 64 + s] = v[q].z;
            x_lds[(d0 + 4*q + 3) * 64 + s] = v[q].w;
        }
    }
    __syncthreads();

    float best[8];
    int   bidx[8];
#pragma unroll
    for (int i = 0; i < 8; ++i) { best[i] = 3.4e38f; bidx[i] = 0; }

    // ---- 4 tiles of 256 codes; thread's codes k = t*256 + j*32 + kg ----
    for (int t = 0; t < 4; ++t) {
        float acc[8][8];
#pragma unroll
        for (int i = 0; i < 8; ++i)
#pragma unroll
            for (int j = 0; j < 8; ++j) acc[i][j] = 0.f;

        const float* mbase = ct + (size_t)(t*256 + kg) * D;
        float cnv[8];
#pragma unroll
        for (int j = 0; j < 8; ++j) cnv[j] = cnorm[t*256 + j*32 + kg];

#pragma unroll 2
        for (int dc = 0; dc < 16; ++dc) {       // 16 chunks of 4 dims
            // batch-load the 8 m-fragments for this chunk (8 loads in flight)
            float4 mf[8];
#pragma unroll
            for (int j = 0; j < 8; ++j)
                mf[j] = *(const float4*)(mbase + j*32*D + dc*4);
#pragma unroll
            for (int dd = 0; dd < 4; ++dd) {
                const float* xr = x_lds + (dc*4 + dd)*64 + sg*8;
                float4 xa = *(const float4*)(xr);
                float4 xb = *(const float4*)(xr + 4);
#pragma unroll
                for (int j = 0; j < 8; ++j) {
                    const float ms = (dd == 0) ? mf[j].x :
                                     (dd == 1) ? mf[j].y :
                                     (dd == 2) ? mf[j].z : mf[j].w;
                    acc[0][j] = fmaf(xa.x, ms, acc[0][j]);
                    acc[1][j] = fmaf(xa.y, ms, acc[1][j]);
                    acc[2][j] = fmaf(xa.z, ms, acc[2][j]);
                    acc[3][j] = fmaf(xa.w, ms, acc[3][j]);
                    acc[4][j] = fmaf(xb.x, ms, acc[4][j]);
                    acc[5][j] = fmaf(xb.y, ms, acc[5][j]);
                    acc[6][j] = fmaf(xb.z, ms, acc[6][j]);
                    acc[7][j] = fmaf(xb.w, ms, acc[7][j]);
                }
            }
        }
        // distances + running argmin (j ascending => k ascending, strict <)
#pragma unroll
        for (int j = 0; j < 8; ++j) {
            const int k = t*256 + j*32 + kg;
#pragma unroll
            for (int i = 0; i < 8; ++i) {
                float dist = fmaf(-2.f, acc[i][j], cnv[j]);
                if (dist < best[i]) { best[i] = dist; bidx[i] = k; }
            }
        }
    }

    // ---- combine across the 32 kg-threads per sample ----
#pragma unroll
    for (int i = 0; i < 8; ++i) {
        sbv[kg][sg*8 + i] = best[i];
        siv[kg][sg*8 + i] = bidx[i];
    }
    __syncthreads();
    if (tx < 64) {
        float b = sbv[0][tx];
        int   w = siv[0][tx];
#pragma unroll
        for (int p = 1; p < 32; ++p) {
            float bp = sbv[p][tx];
            if (bp < b) { b = bp; w = siv[p][tx]; }
        }
        widx[tx] = w;
    }
    __syncthreads();

    // ---- gather + STE output + loss partial (identical to R1) ----
    const int sl = tx >> 2;                 // local sample 0..63
    const int d0 = (tx & 3) * 16;           // dim offset
    const int gs = blockIdx.x * 64 + sl;
    const int w  = widx[sl];
    const float* mq = ct + ((size_t)w << 6) + d0;
    const float* xr = xin + (size_t)gs * D + d0;
    float*       oq = outq + (size_t)gs * D + d0;
    float psum = 0.f;
#pragma unroll
    for (int j = 0; j < 16; j += 4) {
        float4 q  = *(const float4*)(mq + j);
        float4 xv = *(const float4*)(xr + j);
        float4 o;
        float dx = q.x - xv.x, dy = q.y - xv.y, dz = q.z - xv.z, dw = q.w - xv.w;
        o.x = xv.x + dx; o.y = xv.y + dy; o.z = xv.z + dz; o.w = xv.w + dw;
        *(float4*)(oq + j) = o;
        psum = fmaf(dx, dx, psum);
        psum = fmaf(dy, dy, psum);
        psum = fmaf(dz, dz, psum);
        psum = fmaf(dw, dw, psum);
    }

    if (tx < 64)
        outidx[blockIdx.x * 64 + tx] = (float)widx[tx];

    red[tx] = psum;
    __syncthreads();
    for (int st = 128; st > 0; st >>= 1) {
        if (tx < st) red[tx] += red[tx + st];
        __syncthreads();
    }
    if (tx == 0) atomicAdd(acc_g, (double)red[0]);
}

// ---------------------------------------------------------------------------
// Finalize: loss = m + 0.25*m where m = mean((q-x)^2)
// ---------------------------------------------------------------------------
__global__ void vq_finalize(const double* __restrict__ acc,
                            float* __restrict__ loss_out)
{
    float m = (float)(*acc / (double)NEL);
    *loss_out = m + 0.25f * m;
}

extern "C" void kernel_launch(void* const* d_in, const int* in_sizes, int n_in,
                              void* d_out, int out_size, void* d_ws, size_t ws_size,
                              hipStream_t stream) {
    const float* xin = (const float*)d_in[0];   // [16,64,64,64] fp32
    const float* cm  = (const float*)d_in[1];   // [64,1024] fp32

    float* out     = (float*)d_out;
    float* outq    = out;                 // 4194304 floats
    float* outidx  = out + NEL;           // 65536 floats (indices)
    float* outloss = out + NEL + NS;      // 1 float

    float*  ct    = (float*)d_ws;         // 65536 floats = 256 KB
    float*  cnorm = ct + (size_t)K * D;   // 1024 floats
    double* acc   = (double*)(cnorm + K); // 8B-aligned

    vq_prep<<<4, 256, 0, stream>>>(cm, ct, cnorm, acc);
    vq_main<<<1024, 256, 0, stream>>>(xin, ct, cnorm, outq, outidx, acc);
    vq_finalize<<<1, 1, 0, stream>>>(acc, outloss);
}

// Round 4
// 206.639 us; speedup vs baseline: 2.7074x; 1.0182x over previous
//
#include <hip/hip_runtime.h>

#define NS 65536      // B*H*W samples
#define D 64          // embed dim
#define K 1024        // codebook size
#define NEL 4194304   // NS*D

// ---------------------------------------------------------------------------
// Prep: transpose codebook [D,K] -> [K,D] (contiguous 256B rows), compute
// ||m_k||^2, zero the loss accumulator.
// ---------------------------------------------------------------------------
__global__ __launch_bounds__(256) void vq_prep(
    const float* __restrict__ cm,   // [D,K]
    float* __restrict__ ct,         // [K,D]
    float* __restrict__ cnorm,      // [K]
    double* __restrict__ acc)
{
    const int k = blockIdx.x * 256 + threadIdx.x;   // 4 blocks x 256 = 1024
    if (k == 0) *acc = 0.0;
    float vals[D];
    float n = 0.f;
#pragma unroll
    for (int d = 0; d < D; ++d) {
        float v = cm[d * K + k];    // coalesced across k
        vals[d] = v;
        n = fmaf(v, v, n);
    }
    cnorm[k] = n;
    float4* dst = (float4*)(ct + (size_t)k * D);
#pragma unroll
    for (int j = 0; j < D / 4; ++j)
        dst[j] = make_float4(vals[4*j], vals[4*j+1], vals[4*j+2], vals[4*j+3]);
}

// ---------------------------------------------------------------------------
// Main: register-tiled VALU GEMM. 1024 blocks x 256 threads.
// Block = 64 samples x 1024 codes (4 tiles of 256). Thread = 8 samples x 8
// codes (64 fp32 accumulators). x staged transposed [d][s] in LDS (2-way
// bank reads = free); m rows streamed per-lane-distinct from L2-resident ct.
// launch_bounds(256,2): VGPR cap 256 — R2's (256,3) cap of 170 caused
// scratch spill of the accumulator tile (VGPR_Count 84 + 90MB spill writes).
// ---------------------------------------------------------------------------
__global__ __launch_bounds__(256, 2) void vq_main(
    const float* __restrict__ xin,    // [NS,D]
    const float* __restrict__ ct,     // [K,D]
    const float* __restrict__ cnorm,  // [K]
    float* __restrict__ outq,         // [NS,D]
    float* __restrict__ outidx,       // [NS] (indices as float)
    double* __restrict__ acc_g)
{
    __shared__ float x_lds[D * 64];   // [d][s], 16 KB
    __shared__ float sbv[32][64];
    __shared__ int   siv[32][64];
    __shared__ int   widx[64];
    __shared__ float red[256];

    const int tx = threadIdx.x;
    const int sg = tx & 7;      // sample octet 0..7  (8 samples each)
    const int kg = tx >> 3;     // code lane 0..31
    const int S0 = blockIdx.x * 64;

    // ---- stage x transposed into LDS: [d][s] ----
    {
        const int s  = tx >> 2;          // 0..63
        const int d0 = (tx & 3) * 16;    // 0/16/32/48
        const float* gp = xin + (size_t)(S0 + s) * D + d0;
        float4 v[4];
#pragma unroll
        for (int q = 0; q < 4; ++q) v[q] = ((const float4*)gp)[q];
#pragma unroll
        for (int q = 0; q < 4; ++q) {
            x_lds[(d0 + 4*q + 0) * 64 + s] = v[q].x;
            x_lds[(d0 + 4*q + 1) * 64 + s] = v[q].y;
            x_lds[(d0 + 4*q + 2) * 64 + s] = v[q].z;
            x_lds[(d0 + 4*q + 3) * 64 + s] = v[q].w;
        }
    }
    __syncthreads();

    float best[8];
    int   bidx[8];
#pragma unroll
    for (int i = 0; i < 8; ++i) { best[i] = 3.4e38f; bidx[i] = 0; }

    // ---- 4 tiles of 256 codes; thread's codes k = t*256 + j*32 + kg ----
    for (int t = 0; t < 4; ++t) {
        float acc[8][8];
#pragma unroll
        for (int i = 0; i < 8; ++i)
#pragma unroll
            for (int j = 0; j < 8; ++j) acc[i][j] = 0.f;

        const float* mbase = ct + (size_t)(t*256 + kg) * D;
        float cnv[8];
#pragma unroll
        for (int j = 0; j < 8; ++j) cnv[j] = cnorm[t*256 + j*32 + kg];

        for (int dc = 0; dc < 16; ++dc) {       // 16 chunks of 4 dims
            // batch-load the 8 m-fragments for this chunk (8 loads in flight)
            float4 mf[8];
#pragma unroll
            for (int j = 0; j < 8; ++j)
                mf[j] = *(const float4*)(mbase + j*32*D + dc*4);
#pragma unroll
            for (int dd = 0; dd < 4; ++dd) {
                const float* xr = x_lds + (dc*4 + dd)*64 + sg*8;
                float4 xa = *(const float4*)(xr);
                float4 xb = *(const float4*)(xr + 4);
#pragma unroll
                for (int j = 0; j < 8; ++j) {
                    const float ms = (dd == 0) ? mf[j].x :
                                     (dd == 1) ? mf[j].y :
                                     (dd == 2) ? mf[j].z : mf[j].w;
                    acc[0][j] = fmaf(xa.x, ms, acc[0][j]);
                    acc[1][j] = fmaf(xa.y, ms, acc[1][j]);
                    acc[2][j] = fmaf(xa.z, ms, acc[2][j]);
                    acc[3][j] = fmaf(xa.w, ms, acc[3][j]);
                    acc[4][j] = fmaf(xb.x, ms, acc[4][j]);
                    acc[5][j] = fmaf(xb.y, ms, acc[5][j]);
                    acc[6][j] = fmaf(xb.z, ms, acc[6][j]);
                    acc[7][j] = fmaf(xb.w, ms, acc[7][j]);
                }
            }
        }
        // distances + running argmin (j ascending => k ascending, strict <)
#pragma unroll
        for (int j = 0; j < 8; ++j) {
            const int k = t*256 + j*32 + kg;
#pragma unroll
            for (int i = 0; i < 8; ++i) {
                float dist = fmaf(-2.f, acc[i][j], cnv[j]);
                if (dist < best[i]) { best[i] = dist; bidx[i] = k; }
            }
        }
    }

    // ---- combine across the 32 kg-threads per sample ----
#pragma unroll
    for (int i = 0; i < 8; ++i) {
        sbv[kg][sg*8 + i] = best[i];
        siv[kg][sg*8 + i] = bidx[i];
    }
    __syncthreads();
    if (tx < 64) {
        float b = sbv[0][tx];
        int   w = siv[0][tx];
#pragma unroll
        for (int p = 1; p < 32; ++p) {
            float bp = sbv[p][tx];
            if (bp < b) { b = bp; w = siv[p][tx]; }
        }
        widx[tx] = w;
    }
    __syncthreads();

    // ---- gather + STE output + loss partial (identical to R1) ----
    const int sl = tx >> 2;                 // local sample 0..63
    const int d0 = (tx & 3) * 16;           // dim offset
    const int gs = blockIdx.x * 64 + sl;
    const int w  = widx[sl];
    const float* mq = ct + ((size_t)w << 6) + d0;
    const float* xr = xin + (size_t)gs * D + d0;
    float*       oq = outq + (size_t)gs * D + d0;
    float psum = 0.f;
#pragma unroll
    for (int j = 0; j < 16; j += 4) {
        float4 q  = *(const float4*)(mq + j);
        float4 xv = *(const float4*)(xr + j);
        float4 o;
        float dx = q.x - xv.x, dy = q.y - xv.y, dz = q.z - xv.z, dw = q.w - xv.w;
        o.x = xv.x + dx; o.y = xv.y + dy; o.z = xv.z + dz; o.w = xv.w + dw;
        *(float4*)(oq + j) = o;
        psum = fmaf(dx, dx, psum);
        psum = fmaf(dy, dy, psum);
        psum = fmaf(dz, dz, psum);
        psum = fmaf(dw, dw, psum);
    }

    if (tx < 64)
        outidx[blockIdx.x * 64 + tx] = (float)widx[tx];

    red[tx] = psum;
    __syncthreads();
    for (int st = 128; st > 0; st >>= 1) {
        if (tx < st) red[tx] += red[tx + st];
        __syncthreads();
    }
    if (tx == 0) atomicAdd(acc_g, (double)red[0]);
}

// ---------------------------------------------------------------------------
// Finalize: loss = m + 0.25*m where m = mean((q-x)^2)
// ---------------------------------------------------------------------------
__global__ void vq_finalize(const double* __restrict__ acc,
                            float* __restrict__ loss_out)
{
    float m = (float)(*acc / (double)NEL);
    *loss_out = m + 0.25f * m;
}

extern "C" void kernel_launch(void* const* d_in, const int* in_sizes, int n_in,
                              void* d_out, int out_size, void* d_ws, size_t ws_size,
                              hipStream_t stream) {
    const float* xin = (const float*)d_in[0];   // [16,64,64,64] fp32
    const float* cm  = (const float*)d_in[1];   // [64,1024] fp32

    float* out     = (float*)d_out;
    float* outq    = out;                 // 4194304 floats
    float* outidx  = out + NEL;           // 65536 floats (indices)
    float* outloss = out + NEL + NS;      // 1 float

    float*  ct    = (float*)d_ws;         // 65536 floats = 256 KB
    float*  cnorm = ct + (size_t)K * D;   // 1024 floats
    double* acc   = (double*)(cnorm + K); // 8B-aligned

    vq_prep<<<4, 256, 0, stream>>>(cm, ct, cnorm, acc);
    vq_main<<<1024, 256, 0, stream>>>(xin, ct, cnorm, outq, outidx, acc);
    vq_finalize<<<1, 1, 0, stream>>>(acc, outloss);
}

// Round 5
// 193.733 us; speedup vs baseline: 2.8878x; 1.0666x over previous
//
#include <hip/hip_runtime.h>

#define NS 65536      // B*H*W samples
#define D 64          // embed dim
#define K 1024        // codebook size
#define NEL 4194304   // NS*D

// ---------------------------------------------------------------------------
// Prep: transpose codebook [D,K] -> [K,D] (contiguous 256B rows), compute
// ||m_k||^2, zero the loss accumulator.
// ---------------------------------------------------------------------------
__global__ __launch_bounds__(256) void vq_prep(
    const float* __restrict__ cm,   // [D,K]
    float* __restrict__ ct,         // [K,D]
    float* __restrict__ cnorm,      // [K]
    double* __restrict__ acc)
{
    const int k = blockIdx.x * 256 + threadIdx.x;   // 4 blocks x 256 = 1024
    if (k == 0) *acc = 0.0;
    float vals[D];
    float n = 0.f;
#pragma unroll
    for (int d = 0; d < D; ++d) {
        float v = cm[d * K + k];    // coalesced across k
        vals[d] = v;
        n = fmaf(v, v, n);
    }
    cnorm[k] = n;
    float4* dst = (float4*)(ct + (size_t)k * D);
#pragma unroll
    for (int j = 0; j < D / 4; ++j)
        dst[j] = make_float4(vals[4*j], vals[4*j+1], vals[4*j+2], vals[4*j+3]);
}

// ---------------------------------------------------------------------------
// Main: register-tiled VALU GEMM. 1024 blocks x 256 threads.
// Block = 64 samples x 1024 codes (4 tiles of 256). Thread = 8 samples x 8
// codes (64 fp32 accumulators).
// R4 changes vs R3: launch_bounds(256,3) [cap 170 >= ~150 demand, no spill,
// >=3 waves/SIMD]; m-fragments loaded in two j-halves (peak mf liveness
// 32->16 regs, aiming for <=128 total -> 4 waves/SIMD); cnorm in LDS (frees
// 8 regs); x_lds aliased with sbv/siv/red reduction buffers (LDS 34->21 KB).
// ---------------------------------------------------------------------------
__global__ __launch_bounds__(256, 3) void vq_main(
    const float* __restrict__ xin,    // [NS,D]
    const float* __restrict__ ct,     // [K,D]
    const float* __restrict__ cnorm,  // [K]
    float* __restrict__ outq,         // [NS,D]
    float* __restrict__ outidx,       // [NS] (indices as float)
    double* __restrict__ acc_g)
{
    // Region A (16 KB): x_lds[4096] during GEMM; after a barrier, reused as
    // sbv[32][64] (8 KB) + siv[32][64] (8 KB); after the widx barrier the
    // first 1 KB is reused again as red[256].
    __shared__ float smemA[4096];
    __shared__ float cn_lds[1024];    // 4 KB
    __shared__ int   widx[64];

    float* x_lds = smemA;                    // [d][s]
    float* sbv   = smemA;                    // [32][64]
    int*   siv   = (int*)(smemA + 2048);     // [32][64]
    float* red   = smemA;                    // [256], after sbv is dead

    const int tx = threadIdx.x;
    const int sg = tx & 7;      // sample octet 0..7  (8 samples each)
    const int kg = tx >> 3;     // code lane 0..31
    const int S0 = blockIdx.x * 64;

    // ---- stage x transposed into LDS [d][s]; stage cnorm ----
    {
        const int s  = tx >> 2;          // 0..63
        const int d0 = (tx & 3) * 16;    // 0/16/32/48
        const float* gp = xin + (size_t)(S0 + s) * D + d0;
        float4 v[4];
#pragma unroll
        for (int q = 0; q < 4; ++q) v[q] = ((const float4*)gp)[q];
#pragma unroll
        for (int q = 0; q < 4; ++q) {
            x_lds[(d0 + 4*q + 0) * 64 + s] = v[q].x;
            x_lds[(d0 + 4*q + 1) * 64 + s] = v[q].y;
            x_lds[(d0 + 4*q + 2) * 64 + s] = v[q].z;
            x_lds[(d0 + 4*q + 3) * 64 + s] = v[q].w;
        }
#pragma unroll
        for (int q = 0; q < 4; ++q) cn_lds[q*256 + tx] = cnorm[q*256 + tx];
    }
    __syncthreads();

    float best[8];
    int   bidx[8];
#pragma unroll
    for (int i = 0; i < 8; ++i) { best[i] = 3.4e38f; bidx[i] = 0; }

    // ---- 4 tiles of 256 codes; thread's codes k = t*256 + j*32 + kg ----
    for (int t = 0; t < 4; ++t) {
        float acc[8][8];
#pragma unroll
        for (int i = 0; i < 8; ++i)
#pragma unroll
            for (int j = 0; j < 8; ++j) acc[i][j] = 0.f;

        const float* mbase = ct + (size_t)(t*256 + kg) * D;

        for (int dc = 0; dc < 16; ++dc) {       // 16 chunks of 4 dims
#pragma unroll
            for (int h = 0; h < 2; ++h) {       // two j-halves of 4 codes
                float4 mf[4];
#pragma unroll
                for (int j = 0; j < 4; ++j)
                    mf[j] = *(const float4*)(mbase + (h*4 + j)*32*D + dc*4);
#pragma unroll
                for (int dd = 0; dd < 4; ++dd) {
                    const float* xr = x_lds + (dc*4 + dd)*64 + sg*8;
                    float4 xa = *(const float4*)(xr);
                    float4 xb = *(const float4*)(xr + 4);
#pragma unroll
                    for (int j = 0; j < 4; ++j) {
                        const float ms = (dd == 0) ? mf[j].x :
                                         (dd == 1) ? mf[j].y :
                                         (dd == 2) ? mf[j].z : mf[j].w;
                        const int jj = h*4 + j;
                        acc[0][jj] = fmaf(xa.x, ms, acc[0][jj]);
                        acc[1][jj] = fmaf(xa.y, ms, acc[1][jj]);
                        acc[2][jj] = fmaf(xa.z, ms, acc[2][jj]);
                        acc[3][jj] = fmaf(xa.w, ms, acc[3][jj]);
                        acc[4][jj] = fmaf(xb.x, ms, acc[4][jj]);
                        acc[5][jj] = fmaf(xb.y, ms, acc[5][jj]);
                        acc[6][jj] = fmaf(xb.z, ms, acc[6][jj]);
                        acc[7][jj] = fmaf(xb.w, ms, acc[7][jj]);
                    }
                }
            }
        }
        // distances + running argmin (j ascending => k ascending, strict <)
#pragma unroll
        for (int j = 0; j < 8; ++j) {
            const int k = t*256 + j*32 + kg;
            const float cnv = cn_lds[k];
#pragma unroll
            for (int i = 0; i < 8; ++i) {
                float dist = fmaf(-2.f, acc[i][j], cnv);
                if (dist < best[i]) { best[i] = dist; bidx[i] = k; }
            }
        }
    }

    // ---- combine across the 32 kg-threads per sample ----
    __syncthreads();   // x_lds dead everywhere before sbv/siv overwrite it
#pragma unroll
    for (int i = 0; i < 8; ++i) {
        sbv[kg*64 + sg*8 + i] = best[i];
        siv[kg*64 + sg*8 + i] = bidx[i];
    }
    __syncthreads();
    if (tx < 64) {
        float b = sbv[tx];
        int   w = siv[tx];
#pragma unroll
        for (int p = 1; p < 32; ++p) {
            float bp = sbv[p*64 + tx];
            if (bp < b) { b = bp; w = siv[p*64 + tx]; }
        }
        widx[tx] = w;
    }
    __syncthreads();   // after this, sbv/siv dead -> red may reuse region

    // ---- gather + STE output + loss partial ----
    const int sl = tx >> 2;                 // local sample 0..63
    const int d0 = (tx & 3) * 16;           // dim offset
    const int gs = blockIdx.x * 64 + sl;
    const int w  = widx[sl];
    const float* mq = ct + ((size_t)w << 6) + d0;
    const float* xr = xin + (size_t)gs * D + d0;
    float*       oq = outq + (size_t)gs * D + d0;
    float psum = 0.f;
#pragma unroll
    for (int j = 0; j < 16; j += 4) {
        float4 q  = *(const float4*)(mq + j);
        float4 xv = *(const float4*)(xr + j);
        float4 o;
        float dx = q.x - xv.x, dy = q.y - xv.y, dz = q.z - xv.z, dw = q.w - xv.w;
        o.x = xv.x + dx; o.y = xv.y + dy; o.z = xv.z + dz; o.w = xv.w + dw;
        *(float4*)(oq + j) = o;
        psum = fmaf(dx, dx, psum);
        psum = fmaf(dy, dy, psum);
        psum = fmaf(dz, dz, psum);
        psum = fmaf(dw, dw, psum);
    }

    if (tx < 64)
        outidx[blockIdx.x * 64 + tx] = (float)widx[tx];

    red[tx] = psum;
    __syncthreads();
    for (int st = 128; st > 0; st >>= 1) {
        if (tx < st) red[tx] += red[tx + st];
        __syncthreads();
    }
    if (tx == 0) atomicAdd(acc_g, (double)red[0]);
}

// ---------------------------------------------------------------------------
// Finalize: loss = m + 0.25*m where m = mean((q-x)^2)
// ---------------------------------------------------------------------------
__global__ void vq_finalize(const double* __restrict__ acc,
                            float* __restrict__ loss_out)
{
    float m = (float)(*acc / (double)NEL);
    *loss_out = m + 0.25f * m;
}

extern "C" void kernel_launch(void* const* d_in, const int* in_sizes, int n_in,
                              void* d_out, int out_size, void* d_ws, size_t ws_size,
                              hipStream_t stream) {
    const float* xin = (const float*)d_in[0];   // [16,64,64,64] fp32
    const float* cm  = (const float*)d_in[1];   // [64,1024] fp32

    float* out     = (float*)d_out;
    float* outq    = out;                 // 4194304 floats
    float* outidx  = out + NEL;           // 65536 floats (indices)
    float* outloss = out + NEL + NS;      // 1 float

    float*  ct    = (float*)d_ws;         // 65536 floats = 256 KB
    float*  cnorm = ct + (size_t)K * D;   // 1024 floats
    double* acc   = (double*)(cnorm + K); // 8B-aligned

    vq_prep<<<4, 256, 0, stream>>>(cm, ct, cnorm, acc);
    vq_main<<<1024, 256, 0, stream>>>(xin, ct, cnorm, outq, outidx, acc);
    vq_finalize<<<1, 1, 0, stream>>>(acc, outloss);
}